// Round 12
// baseline (393.124 us; speedup 1.0000x reference)
//
#include <hip/hip_runtime.h>
#include <hip/hip_fp16.h>
#include <float.h>

#define MKEY 256        // K (key size)
#define NMEM 100000     // memory rows
#define NPAD 100096     // 782 * 128
#define NQ   2048       // queries
#define BM 128
#define BN 128
#define NTILES 782      // NPAD / BN : 128-row blocks
#define BLKPAD 800      // padded row stride for bmaxQ
#define GRID (128 * 98) // XCD-clustered id space; ntile>=782 early-exits
#define KB16 (NPAD / 16)       // 6256 convert key-blocks (16 rows each)
#define QS (127.0f / 6.0f)     // i8 quant scale (data ~N(0,1), clamp at 6 sigma)
#define SS2 ((6.0f / 127.0f) * (6.0f / 127.0f))  // dequant: dot_f = dot_i8 * SS2
#define GDELTA 0.04f    // group-code quantum (ub = bmax - code*GDELTA >= gmax)
#define GINVD  25.0f

typedef int i32x4 __attribute__((ext_vector_type(4)));

__device__ inline void gll16(const void* g, void* l) {
  __builtin_amdgcn_global_load_lds(
      (const __attribute__((address_space(1))) unsigned*)g,
      (__attribute__((address_space(3))) unsigned*)l, 16, 0, 0);
}

__device__ inline int pack_i8x4(float4 v) {
  int c0 = max(-127, min(127, __float2int_rn(v.x * QS)));
  int c1 = max(-127, min(127, __float2int_rn(v.y * QS)));
  int c2 = max(-127, min(127, __float2int_rn(v.z * QS)));
  int c3 = max(-127, min(127, __float2int_rn(v.w * QS)));
  return (c0 & 255) | ((c1 & 255) << 8) | ((c2 & 255) << 16) | ((c3 & 255) << 24);
}

// signed 4x i8 dot; HW v_dot4 when available (i32 result exact either way)
__device__ inline int dot4i8(int a, int b, int s) {
#if __has_builtin(__builtin_amdgcn_sdot4)
  return __builtin_amdgcn_sdot4(a, b, s, false);
#else
#pragma unroll
  for (int k = 0; k < 4; ++k) {
    const int av = (a << (24 - 8 * k)) >> 24;
    const int bv = (b << (24 - 8 * k)) >> 24;
    s += av * bv;
  }
  return s;
#endif
}

// merged convert: keys fp32 -> i8 + inv key norm, 16 lanes per row.
__global__ void convert(const float* __restrict__ q, const float* __restrict__ mem,
                        int* __restrict__ qi, int* __restrict__ ki,
                        float* __restrict__ rkn) {
  const int b = blockIdx.x, t = threadIdx.x;
  if (b >= KB16) {
    const int i = (b - KB16) * 256 + t;   // int4-group index
    const float4 v = *(const float4*)&q[(size_t)i * 4];
    qi[i] = pack_i8x4(v);
    return;
  }
  const int row = b * 16 + (t >> 4);
  const int c = t & 15;                   // 16-float chunk of the row
  if (row < NMEM) {
    const float* src = &mem[(size_t)row * 512 + c * 16];
    const float4 v0 = *(const float4*)&src[0];
    const float4 v1 = *(const float4*)&src[4];
    const float4 v2 = *(const float4*)&src[8];
    const float4 v3 = *(const float4*)&src[12];
    float ss = v0.x * v0.x + v0.y * v0.y + v0.z * v0.z + v0.w * v0.w +
               v1.x * v1.x + v1.y * v1.y + v1.z * v1.z + v1.w * v1.w +
               v2.x * v2.x + v2.y * v2.y + v2.z * v2.z + v2.w * v2.w +
               v3.x * v3.x + v3.y * v3.y + v3.z * v3.z + v3.w * v3.w;
#pragma unroll
    for (int off = 8; off >= 1; off >>= 1) ss += __shfl_xor(ss, off, 64);
    int4 pk;
    pk.x = pack_i8x4(v0); pk.y = pack_i8x4(v1);
    pk.z = pack_i8x4(v2); pk.w = pack_i8x4(v3);
    *(int4*)&ki[(size_t)row * 64 + c * 4] = pk;
    if (c == 0) rkn[row] = 1.0f / sqrtf(fmaxf(ss, 1e-30f));
  } else {
    *(int4*)&ki[(size_t)row * 64 + c * 4] = make_int4(0, 0, 0, 0);
    if (c == 0) rkn[row] = 0.f;
  }
}

// Pass 1: i8 screening GEMM (mfma_i32_16x16x64_i8). 128x128 tile, 4 waves.
// R10-proven structure; ONE new lever: LDS compacted to exactly 32 KB
// (bhalf moved into the dead zone above the 20480-B L table) so FIVE blocks
// fit one CU's 160-KiB pool -> __launch_bounds__(256,5), 20 waves/CU (+25%
// TLP to hide the per-step barrier drains the last three rounds showed are
// the residual cost; epilogue variants R9/R11 and fine-pipelining were all
// neutral-to-negative).
//   bcode8[nt*NQ + qid] : u64 of 8 per-group codes; ub_g = bmax - code*GDELTA
//   bmaxB [nt*NQ + qid] : per-128-key-block max
__global__ __launch_bounds__(256, 5) void gemm_screen(
    const int* __restrict__ qi, const int* __restrict__ ki,
    const float* __restrict__ rkn,
    unsigned long long* __restrict__ bcode8, float* __restrict__ bmaxB) {
  // bufA[p] at p*8192; bufB[p] at 16384+p*8192.  Epilogue overlays:
  // L (20480 B) at 0; bhalf (1024 B) at 20480  — total 32768 B exactly.
  __shared__ __align__(128) char smem[32768];

  const int id = blockIdx.x;
  const int mtile = (id >> 3) & 15;
  const int ntile = (id & 7) + 8 * (id >> 7);
  if (ntile >= NTILES) return;

  const int t = threadIdx.x;
  const int w = t >> 6;
  const int lane = t & 63;
  const int wr = w >> 1, wc = w & 1;
  const int q16 = lane >> 4, l16 = lane & 15;

  // staging: waves 0,1 -> A halves; waves 2,3 -> B halves; 4 gll16 x 1 KB.
  // phys chunk (lane&3) at row holds global chunk (lane&3)^((row>>1)&3);
  // row>>1 within the 8-aligned span reduces to lane>>3. (R10-proven.)
  const int swz64 = ((lane & 3) ^ ((lane >> 3) & 3)) * 16;
  int soff4[4];
#pragma unroll
  for (int c = 0; c < 4; ++c)
    soff4[c] = ((w & 1) * 64 + c * 16 + (lane >> 2)) * 256 + swz64;
  const char* const asrc = (const char*)((w < 2) ? qi : ki) +
                           (size_t)(((w < 2) ? mtile : ntile) * 128) * 256;
  char* const dbase = smem + ((w < 2) ? 0 : 16384) + (w & 1) * 4096;

#define STG(p, s)                                         \
  do {                                                    \
    const char* _s = asrc + (s) * 64;                     \
    char* _d = dbase + (p) * 8192;                        \
    _Pragma("unroll")                                     \
    for (int c = 0; c < 4; ++c)                           \
      gll16(_s + soff4[c], _d + c * 1024);                \
  } while (0)

  i32x4 acc[4][4];
#pragma unroll
  for (int i = 0; i < 4; i++)
#pragma unroll
    for (int j = 0; j < 4; j++) acc[i][j] = (i32x4){0, 0, 0, 0};

  // ds_read phys chunk: logical chunk q16 -> q16 ^ ((row>>1)&3) = q16^((l16>>1)&3)
  const int pc4 = (q16 ^ ((l16 >> 1) & 3)) * 16;

  STG(0, 0);
  __syncthreads();                       // prologue drain (vmcnt via compiler)
#pragma unroll
  for (int s = 0; s < 4; ++s) {          // 4 K-steps of 64
    if (s < 3) STG((s + 1) & 1, s + 1);  // prefetch next, other buffer
    const int p = (s & 1) * 8192;
    i32x4 av[4], bv[4];
#pragma unroll
    for (int i = 0; i < 4; i++)
      av[i] = *(const i32x4*)&smem[p + (64 * wr + 16 * i + l16) * 64 + pc4];
#pragma unroll
    for (int j = 0; j < 4; j++)
      bv[j] = *(const i32x4*)&smem[16384 + p + (64 * wc + 16 * j + l16) * 64 + pc4];
#pragma unroll
    for (int i = 0; i < 4; i++)
#pragma unroll
      for (int j = 0; j < 4; j++)
        acc[i][j] = __builtin_amdgcn_mfma_i32_16x16x64_i8(av[i], bv[j], acc[i][j], 0, 0, 0);
    __syncthreads();                     // drains this wave's stage + LDS reads
  }
#undef STG

  // ---- Epilogue (R8/R10-proven LDS reduction + code packing) ----
  float rk[4];
#pragma unroll
  for (int j = 0; j < 4; j++) {
    const int ncol = ntile * BN + 64 * wc + 16 * j + l16;
    rk[j] = (ncol < NMEM) ? rkn[ncol] * SS2 : 0.f;   // padded cols -> exactly 0.0
  }
  float (*L)[20] = (float(*)[20])smem;     // 256 rows x 20 floats = 20480 B
  float* bhalf = (float*)(smem + 20480);   // [w][qrow][i] : 1024 B (dead zone)
  const int wr_ = t >> 7, gg = (t >> 4) & 7, qrow = t & 15;
  float outv[4];
#pragma unroll
  for (int i = 0; i < 4; ++i) {
#pragma unroll
    for (int j = 0; j < 4; ++j)
#pragma unroll
      for (int r = 0; r < 4; ++r)
        L[(wr * 8 + wc * 4 + j) * 16 + q16 * 4 + r][l16] = (float)acc[i][j][r] * rk[j];
    __syncthreads();
    const float* Lr = L[(wr_ * 8 + gg) * 16 + qrow];
    const float4 a = *(const float4*)&Lr[0], b4 = *(const float4*)&Lr[4];
    const float4 cc = *(const float4*)&Lr[8], dd = *(const float4*)&Lr[12];
    float m = fmaxf(fmaxf(fmaxf(a.x, a.y), fmaxf(a.z, a.w)),
                    fmaxf(fmaxf(b4.x, b4.y), fmaxf(b4.z, b4.w)));
    m = fmaxf(m, fmaxf(fmaxf(cc.x, cc.y), fmaxf(cc.z, cc.w)));
    m = fmaxf(m, fmaxf(fmaxf(dd.x, dd.y), fmaxf(dd.z, dd.w)));
    outv[i] = m;                          // group gg max, row wr_*64+i*16+qrow
    float bm = fmaxf(m, __shfl_xor(m, 16, 64));
    bm = fmaxf(bm, __shfl_xor(bm, 32, 64));
    if (lane < 16) bhalf[(w * 16 + lane) * 4 + i] = bm;
    __syncthreads();
  }
  // block max per row -> LDS brow (overlays dead L rows) + global bmaxB
  float* brow = (float*)smem;                       // 128 floats
  unsigned char* cb = (unsigned char*)(smem + 512); // 128 x 8 codes
  if (t < 128) {
    const int wrb = t >> 6, ib = (t >> 4) & 3, qr = t & 15;
    const float v = fmaxf(bhalf[((2 * wrb) * 16 + qr) * 4 + ib],
                          bhalf[((2 * wrb + 1) * 16 + qr) * 4 + ib]);
    brow[t] = v;
    bmaxB[(size_t)ntile * NQ + mtile * 128 + t] = v;
  }
  __syncthreads();
  // codes: floor((bmax - gmax)/delta), clamped; ub = bmax - code*delta >= gmax
#pragma unroll
  for (int i = 0; i < 4; ++i) {
    const int row = wr_ * 64 + i * 16 + qrow;
    int code = (int)((brow[row] - outv[i]) * GINVD);
    code = min(255, max(0, code));
    cb[row * 8 + gg] = (unsigned char)code;
  }
  __syncthreads();
  if (t < 128)
    bcode8[(size_t)ntile * NQ + mtile * 128 + t] =
        *(const unsigned long long*)&cb[t * 8];   // coalesced 1 KB
}

// bmaxB[782][2048] -> bmaxQ[2048][800] (pad cols 782..799 never read)
__global__ __launch_bounds__(256) void transpose_blk(const float* __restrict__ in,
                                                     float* __restrict__ outp) {
  __shared__ float tl[32][33];
  const int bid = blockIdx.x;
  const int ntt = bid % 25, qt = bid / 25;
  const int r0 = ntt * 32, c0 = qt * 32;
  const int tx = threadIdx.x & 31, ty = threadIdx.x >> 5;   // ty 0..7
#pragma unroll
  for (int k = 0; k < 4; ++k) {
    const int r = r0 + ty + 8 * k;
    tl[ty + 8 * k][tx] = (r < NTILES) ? in[(size_t)r * NQ + c0 + tx] : -FLT_MAX;
  }
  __syncthreads();
#pragma unroll
  for (int k = 0; k < 4; ++k) {
    const int qq = c0 + ty + 8 * k;
    const int nt = r0 + tx;
    if (nt < NTILES) outp[(size_t)qq * BLKPAD + nt] = tl[tx][ty + 8 * k];
  }
}

// Pass 2 per query (1 block), four-level funnel:
//   A)  contiguous bmaxQ scan -> gm, thresh; candidate blocks (~3)
//   B1) decode candidate blocks' u64 group codes: admit group iff
//       bmax - code*GDELTA >= thresh (ub >= gmax always -> truth survives)
//   B2) i8 re-score of candidate groups' 16 rows (bit-identical rounding to
//       the MFMA path) -> row list (~4 rows)
//   C)  exact fp64 cosine for listed rows; argmax, low-index tie-break
// margin 1.8e-2*qn = 14.9 sigma of i8 score error >= 2 x 6.2-sigma bound.
__global__ __launch_bounds__(256) void rescore_gather(
    const float* __restrict__ q, const float* __restrict__ mem,
    const int* __restrict__ qi8, const int* __restrict__ ki8,
    const float* __restrict__ rkn, const float* __restrict__ bmaxQ,
    const unsigned long long* __restrict__ bcode8, float* __restrict__ out) {
  __shared__ float red2[4];
  __shared__ int blist[64];
  __shared__ int nblk;
  __shared__ int glist[128];
  __shared__ int ng;
  __shared__ int rlist[256];
  __shared__ int nrow;
  __shared__ double wb[4];
  __shared__ int wbi[4];
  __shared__ int widx;

  const int qid = blockIdx.x;
  const int t = threadIdx.x, w = t >> 6, lane = t & 63;

  const float4 qv = *(const float4*)&q[(size_t)qid * 256 + lane * 4];
  float ss = qv.x * qv.x + qv.y * qv.y + qv.z * qv.z + qv.w * qv.w;
#pragma unroll
  for (int off = 32; off >= 1; off >>= 1) ss += __shfl_xor(ss, off, 64);
  const float qn = sqrtf(ss);
  const float margin = 1.8e-2f * qn;

  int4 qreg[4];
#pragma unroll
  for (int k = 0; k < 4; ++k)
    qreg[k] = *(const int4*)&qi8[(size_t)qid * 64 + (lane & 3) * 16 + k * 4];

  if (t == 0) { nblk = 0; ng = 0; nrow = 0; }
  const float* bq = &bmaxQ[(size_t)qid * BLKPAD];

  // ---- A ----
  float gm = -FLT_MAX;
  for (int i = t; i < NTILES; i += 256) gm = fmaxf(gm, bq[i]);
#pragma unroll
  for (int off = 32; off >= 1; off >>= 1) gm = fmaxf(gm, __shfl_xor(gm, off, 64));
  if (lane == 0) red2[w] = gm;
  __syncthreads();
  gm = fmaxf(fmaxf(red2[0], red2[1]), fmaxf(red2[2], red2[3]));
  const float thresh = gm - margin;

  for (int i = t; i < NTILES; i += 256)
    if (bq[i] >= thresh) {
      int p = atomicAdd(&nblk, 1);
      if (p < 64) blist[p] = i;
    }
  __syncthreads();
  const int nb_ = min(nblk, 64);

  // ---- B1: decode group codes (u64 broadcast across 8 threads) ----
  for (int idx = t; idx < nb_ * 8; idx += 256) {
    const int nt = blist[idx >> 3], gl = idx & 7;
    const unsigned long long cw = bcode8[(size_t)nt * NQ + qid];
    const int code = (int)((cw >> (8 * gl)) & 255);
    if ((float)code * GDELTA <= bq[nt] - thresh + 1e-6f) {
      int p = atomicAdd(&ng, 1);
      if (p < 128) glist[p] = nt * 8 + gl;   // rows = g*16 + 0..15
    }
  }
  __syncthreads();
  const int ng_ = min(ng, 128);

  // ---- B2: one candidate group per wave pass; 4 lanes per row ----
  for (int c = w; c < ng_; c += 4) {
    const int row = glist[c] * 16 + (lane >> 2);
    int idot = 0;
#pragma unroll
    for (int k = 0; k < 4; ++k) {
      const int4 kv = *(const int4*)&ki8[(size_t)row * 64 + (lane & 3) * 16 + k * 4];
      idot = dot4i8(kv.x, qreg[k].x, idot);
      idot = dot4i8(kv.y, qreg[k].y, idot);
      idot = dot4i8(kv.z, qreg[k].z, idot);
      idot = dot4i8(kv.w, qreg[k].w, idot);
    }
    idot += __shfl_xor(idot, 1, 64);
    idot += __shfl_xor(idot, 2, 64);
    if ((lane & 3) == 0 && row < NMEM) {
      const float sh = (float)idot * (rkn[row] * SS2);  // == gemm's value, bit-exact
      if (sh >= thresh) {
        int p = atomicAdd(&nrow, 1);
        if (p < 256) rlist[p] = row;
      }
    }
  }
  __syncthreads();
  const int nr = min(nrow, 256);

  // ---- C ----
  double bestv = -1e300;
  int bestidx = 0x7fffffff;
  for (int c = w; c < nr; c += 4) {
    const int row = rlist[c];
    const float4 kv = *(const float4*)&mem[(size_t)row * 512 + lane * 4];
    double d = (double)kv.x * qv.x + (double)kv.y * qv.y +
               (double)kv.z * qv.z + (double)kv.w * qv.w;
    double s2 = (double)kv.x * kv.x + (double)kv.y * kv.y +
                (double)kv.z * kv.z + (double)kv.w * kv.w;
#pragma unroll
    for (int off = 32; off >= 1; off >>= 1) {
      d += __shfl_xor(d, off, 64);
      s2 += __shfl_xor(s2, off, 64);
    }
    if (lane == 0) {
      const double score = d / sqrt(s2 > 1e-300 ? s2 : 1e-300);
      if (score > bestv || (score == bestv && row < bestidx)) {
        bestv = score;
        bestidx = row;
      }
    }
  }
  if (lane == 0) { wb[w] = bestv; wbi[w] = bestidx; }
  __syncthreads();
  if (t == 0) {
    double bv = wb[0];
    int bi = wbi[0];
#pragma unroll
    for (int w2 = 1; w2 < 4; ++w2)
      if (wb[w2] > bv || (wb[w2] == bv && wbi[w2] < bi)) {
        bv = wb[w2];
        bi = wbi[w2];
      }
    widx = bi;
  }
  __syncthreads();
  out[(size_t)qid * 256 + t] = mem[(size_t)widx * 512 + 256 + t];
}

extern "C" void kernel_launch(void* const* d_in, const int* in_sizes, int n_in,
                              void* d_out, int out_size, void* d_ws, size_t ws_size,
                              hipStream_t stream) {
  const float* query = (const float*)d_in[0];
  const float* memory = (const float*)d_in[1];
  float* out = (float*)d_out;

  char* p = (char*)d_ws;
  int* qi = (int*)p; p += (size_t)NQ * 64 * 4;               // 2 MB
  int* ki = (int*)p; p += (size_t)NPAD * 64 * 4;             // 25.6 MB
  float* rkn = (float*)p; p += (size_t)NPAD * 4;             // 0.4 MB
  float* bmaxB = (float*)p; p += (size_t)NTILES * NQ * 4;    // 6.4 MB
  float* bmaxQ = (float*)p; p += (size_t)NQ * BLKPAD * 4;    // 6.6 MB
  unsigned long long* bcode8 = (unsigned long long*)p;
  p += (size_t)NTILES * NQ * 8;                              // 12.8 MB

  hipLaunchKernelGGL(convert, dim3(KB16 + NQ * MKEY / 1024), dim3(256), 0, stream,
                     query, memory, qi, ki, rkn);
  hipLaunchKernelGGL(gemm_screen, dim3(GRID), dim3(256), 0, stream,
                     qi, ki, rkn, bcode8, bmaxB);
  hipLaunchKernelGGL(transpose_blk, dim3(25 * 64), dim3(256), 0, stream, bmaxB, bmaxQ);
  hipLaunchKernelGGL(rescore_gather, dim3(NQ), dim3(256), 0, stream,
                     query, memory, qi, ki, rkn, bmaxQ, bcode8, out);
}

// Round 13
// 357.454 us; speedup vs baseline: 1.0998x; 1.0998x over previous
//
#include <hip/hip_runtime.h>
#include <hip/hip_fp16.h>
#include <float.h>

#define MKEY 256        // K (key size)
#define NMEM 100000     // memory rows
#define NPAD 100096     // 782 * 128
#define NQ   2048       // queries
#define BM 128
#define BN 128
#define NTILES 782      // NPAD / BN : 128-row blocks
#define BLKPAD 800      // padded row stride for bmaxQ
#define GRID (128 * 98) // XCD-clustered id space; ntile>=782 early-exits
#define KB16 (NPAD / 16)       // 6256 convert key-blocks (16 rows each)
#define QS (127.0f / 6.0f)     // i8 quant scale (data ~N(0,1), clamp at 6 sigma)
#define SS2 ((6.0f / 127.0f) * (6.0f / 127.0f))  // dequant: dot_f = dot_i8 * SS2
#define GDELTA 0.04f    // group-code quantum (ub = bmax - code*GDELTA >= gmax)
#define GINVD  25.0f

typedef int i32x4 __attribute__((ext_vector_type(4)));

__device__ inline void gll16(const void* g, void* l) {
  __builtin_amdgcn_global_load_lds(
      (const __attribute__((address_space(1))) unsigned*)g,
      (__attribute__((address_space(3))) unsigned*)l, 16, 0, 0);
}

__device__ inline int pack_i8x4(float4 v) {
  int c0 = max(-127, min(127, __float2int_rn(v.x * QS)));
  int c1 = max(-127, min(127, __float2int_rn(v.y * QS)));
  int c2 = max(-127, min(127, __float2int_rn(v.z * QS)));
  int c3 = max(-127, min(127, __float2int_rn(v.w * QS)));
  return (c0 & 255) | ((c1 & 255) << 8) | ((c2 & 255) << 16) | ((c3 & 255) << 24);
}

// signed 4x i8 dot; HW v_dot4 when available (i32 result exact either way)
__device__ inline int dot4i8(int a, int b, int s) {
#if __has_builtin(__builtin_amdgcn_sdot4)
  return __builtin_amdgcn_sdot4(a, b, s, false);
#else
#pragma unroll
  for (int k = 0; k < 4; ++k) {
    const int av = (a << (24 - 8 * k)) >> 24;
    const int bv = (b << (24 - 8 * k)) >> 24;
    s += av * bv;
  }
  return s;
#endif
}

// merged convert: keys fp32 -> i8 + inv key norm, 16 lanes per row.
__global__ void convert(const float* __restrict__ q, const float* __restrict__ mem,
                        int* __restrict__ qi, int* __restrict__ ki,
                        float* __restrict__ rkn) {
  const int b = blockIdx.x, t = threadIdx.x;
  if (b >= KB16) {
    const int i = (b - KB16) * 256 + t;   // int4-group index
    const float4 v = *(const float4*)&q[(size_t)i * 4];
    qi[i] = pack_i8x4(v);
    return;
  }
  const int row = b * 16 + (t >> 4);
  const int c = t & 15;                   // 16-float chunk of the row
  if (row < NMEM) {
    const float* src = &mem[(size_t)row * 512 + c * 16];
    const float4 v0 = *(const float4*)&src[0];
    const float4 v1 = *(const float4*)&src[4];
    const float4 v2 = *(const float4*)&src[8];
    const float4 v3 = *(const float4*)&src[12];
    float ss = v0.x * v0.x + v0.y * v0.y + v0.z * v0.z + v0.w * v0.w +
               v1.x * v1.x + v1.y * v1.y + v1.z * v1.z + v1.w * v1.w +
               v2.x * v2.x + v2.y * v2.y + v2.z * v2.z + v2.w * v2.w +
               v3.x * v3.x + v3.y * v3.y + v3.z * v3.z + v3.w * v3.w;
#pragma unroll
    for (int off = 8; off >= 1; off >>= 1) ss += __shfl_xor(ss, off, 64);
    int4 pk;
    pk.x = pack_i8x4(v0); pk.y = pack_i8x4(v1);
    pk.z = pack_i8x4(v2); pk.w = pack_i8x4(v3);
    *(int4*)&ki[(size_t)row * 64 + c * 4] = pk;
    if (c == 0) rkn[row] = 1.0f / sqrtf(fmaxf(ss, 1e-30f));
  } else {
    *(int4*)&ki[(size_t)row * 64 + c * 4] = make_int4(0, 0, 0, 0);
    if (c == 0) rkn[row] = 0.f;
  }
}

// Pass 1: i8 screening GEMM (mfma_i32_16x16x64_i8). 128x128 tile, 4 waves.
// R10-proven structure; LDS compacted to exactly 32 KB so the LDS limit alone
// allows FIVE blocks/CU (160 KiB / 32 KiB). CRITICAL (R12 lesson):
// __launch_bounds__ stays (256,4) — asking for 5 waves/EU squeezed the
// allocator to 48 VGPR (< the 64 the acc array needs) and spilled the
// accumulators to scratch (WRITE_SIZE 18.8 -> 207 MB, gemm 68 -> 130 us).
// With min=4, the compiler uses its natural 64 VGPR (8 waves/SIMD capacity)
// and HW occupancy = min(LDS=5, VGPR=8) = 5 blocks/CU, no spill.
//   bcode8[nt*NQ + qid] : u64 of 8 per-group codes; ub_g = bmax - code*GDELTA
//   bmaxB [nt*NQ + qid] : per-128-key-block max
__global__ __launch_bounds__(256, 4) void gemm_screen(
    const int* __restrict__ qi, const int* __restrict__ ki,
    const float* __restrict__ rkn,
    unsigned long long* __restrict__ bcode8, float* __restrict__ bmaxB) {
  // bufA[p] at p*8192; bufB[p] at 16384+p*8192.  Epilogue overlays:
  // L (20480 B) at 0; bhalf (1024 B) at 20480  — total 32768 B exactly.
  __shared__ __align__(128) char smem[32768];

  const int id = blockIdx.x;
  const int mtile = (id >> 3) & 15;
  const int ntile = (id & 7) + 8 * (id >> 7);
  if (ntile >= NTILES) return;

  const int t = threadIdx.x;
  const int w = t >> 6;
  const int lane = t & 63;
  const int wr = w >> 1, wc = w & 1;
  const int q16 = lane >> 4, l16 = lane & 15;

  // staging: waves 0,1 -> A halves; waves 2,3 -> B halves; 4 gll16 x 1 KB.
  // phys chunk (lane&3) at row holds global chunk (lane&3)^((row>>1)&3);
  // row>>1 within the 8-aligned span reduces to lane>>3. (R10-proven.)
  const int swz64 = ((lane & 3) ^ ((lane >> 3) & 3)) * 16;
  int soff4[4];
#pragma unroll
  for (int c = 0; c < 4; ++c)
    soff4[c] = ((w & 1) * 64 + c * 16 + (lane >> 2)) * 256 + swz64;
  const char* const asrc = (const char*)((w < 2) ? qi : ki) +
                           (size_t)(((w < 2) ? mtile : ntile) * 128) * 256;
  char* const dbase = smem + ((w < 2) ? 0 : 16384) + (w & 1) * 4096;

#define STG(p, s)                                         \
  do {                                                    \
    const char* _s = asrc + (s) * 64;                     \
    char* _d = dbase + (p) * 8192;                        \
    _Pragma("unroll")                                     \
    for (int c = 0; c < 4; ++c)                           \
      gll16(_s + soff4[c], _d + c * 1024);                \
  } while (0)

  i32x4 acc[4][4];
#pragma unroll
  for (int i = 0; i < 4; i++)
#pragma unroll
    for (int j = 0; j < 4; j++) acc[i][j] = (i32x4){0, 0, 0, 0};

  // ds_read phys chunk: logical chunk q16 -> q16 ^ ((row>>1)&3) = q16^((l16>>1)&3)
  const int pc4 = (q16 ^ ((l16 >> 1) & 3)) * 16;

  STG(0, 0);
  __syncthreads();                       // prologue drain (vmcnt via compiler)
#pragma unroll
  for (int s = 0; s < 4; ++s) {          // 4 K-steps of 64
    if (s < 3) STG((s + 1) & 1, s + 1);  // prefetch next, other buffer
    const int p = (s & 1) * 8192;
    i32x4 av[4], bv[4];
#pragma unroll
    for (int i = 0; i < 4; i++)
      av[i] = *(const i32x4*)&smem[p + (64 * wr + 16 * i + l16) * 64 + pc4];
#pragma unroll
    for (int j = 0; j < 4; j++)
      bv[j] = *(const i32x4*)&smem[16384 + p + (64 * wc + 16 * j + l16) * 64 + pc4];
#pragma unroll
    for (int i = 0; i < 4; i++)
#pragma unroll
      for (int j = 0; j < 4; j++)
        acc[i][j] = __builtin_amdgcn_mfma_i32_16x16x64_i8(av[i], bv[j], acc[i][j], 0, 0, 0);
    __syncthreads();                     // drains this wave's stage + LDS reads
  }
#undef STG

  // ---- Epilogue (R8/R10-proven LDS reduction + code packing) ----
  float rk[4];
#pragma unroll
  for (int j = 0; j < 4; j++) {
    const int ncol = ntile * BN + 64 * wc + 16 * j + l16;
    rk[j] = (ncol < NMEM) ? rkn[ncol] * SS2 : 0.f;   // padded cols -> exactly 0.0
  }
  float (*L)[20] = (float(*)[20])smem;     // 256 rows x 20 floats = 20480 B
  float* bhalf = (float*)(smem + 20480);   // [w][qrow][i] : 1024 B (dead zone)
  const int wr_ = t >> 7, gg = (t >> 4) & 7, qrow = t & 15;
  float outv[4];
#pragma unroll
  for (int i = 0; i < 4; ++i) {
#pragma unroll
    for (int j = 0; j < 4; ++j)
#pragma unroll
      for (int r = 0; r < 4; ++r)
        L[(wr * 8 + wc * 4 + j) * 16 + q16 * 4 + r][l16] = (float)acc[i][j][r] * rk[j];
    __syncthreads();
    const float* Lr = L[(wr_ * 8 + gg) * 16 + qrow];
    const float4 a = *(const float4*)&Lr[0], b4 = *(const float4*)&Lr[4];
    const float4 cc = *(const float4*)&Lr[8], dd = *(const float4*)&Lr[12];
    float m = fmaxf(fmaxf(fmaxf(a.x, a.y), fmaxf(a.z, a.w)),
                    fmaxf(fmaxf(b4.x, b4.y), fmaxf(b4.z, b4.w)));
    m = fmaxf(m, fmaxf(fmaxf(cc.x, cc.y), fmaxf(cc.z, cc.w)));
    m = fmaxf(m, fmaxf(fmaxf(dd.x, dd.y), fmaxf(dd.z, dd.w)));
    outv[i] = m;                          // group gg max, row wr_*64+i*16+qrow
    float bm = fmaxf(m, __shfl_xor(m, 16, 64));
    bm = fmaxf(bm, __shfl_xor(bm, 32, 64));
    if (lane < 16) bhalf[(w * 16 + lane) * 4 + i] = bm;
    __syncthreads();
  }
  // block max per row -> LDS brow (overlays dead L rows) + global bmaxB
  float* brow = (float*)smem;                       // 128 floats
  unsigned char* cb = (unsigned char*)(smem + 512); // 128 x 8 codes
  if (t < 128) {
    const int wrb = t >> 6, ib = (t >> 4) & 3, qr = t & 15;
    const float v = fmaxf(bhalf[((2 * wrb) * 16 + qr) * 4 + ib],
                          bhalf[((2 * wrb + 1) * 16 + qr) * 4 + ib]);
    brow[t] = v;
    bmaxB[(size_t)ntile * NQ + mtile * 128 + t] = v;
  }
  __syncthreads();
  // codes: floor((bmax - gmax)/delta), clamped; ub = bmax - code*delta >= gmax
#pragma unroll
  for (int i = 0; i < 4; ++i) {
    const int row = wr_ * 64 + i * 16 + qrow;
    int code = (int)((brow[row] - outv[i]) * GINVD);
    code = min(255, max(0, code));
    cb[row * 8 + gg] = (unsigned char)code;
  }
  __syncthreads();
  if (t < 128)
    bcode8[(size_t)ntile * NQ + mtile * 128 + t] =
        *(const unsigned long long*)&cb[t * 8];   // coalesced 1 KB
}

// bmaxB[782][2048] -> bmaxQ[2048][800] (pad cols 782..799 never read)
__global__ __launch_bounds__(256) void transpose_blk(const float* __restrict__ in,
                                                     float* __restrict__ outp) {
  __shared__ float tl[32][33];
  const int bid = blockIdx.x;
  const int ntt = bid % 25, qt = bid / 25;
  const int r0 = ntt * 32, c0 = qt * 32;
  const int tx = threadIdx.x & 31, ty = threadIdx.x >> 5;   // ty 0..7
#pragma unroll
  for (int k = 0; k < 4; ++k) {
    const int r = r0 + ty + 8 * k;
    tl[ty + 8 * k][tx] = (r < NTILES) ? in[(size_t)r * NQ + c0 + tx] : -FLT_MAX;
  }
  __syncthreads();
#pragma unroll
  for (int k = 0; k < 4; ++k) {
    const int qq = c0 + ty + 8 * k;
    const int nt = r0 + tx;
    if (nt < NTILES) outp[(size_t)qq * BLKPAD + nt] = tl[tx][ty + 8 * k];
  }
}

// Pass 2 per query (1 block), four-level funnel:
//   A)  contiguous bmaxQ scan -> gm, thresh; candidate blocks (~3)
//   B1) decode candidate blocks' u64 group codes: admit group iff
//       bmax - code*GDELTA >= thresh (ub >= gmax always -> truth survives)
//   B2) i8 re-score of candidate groups' 16 rows (bit-identical rounding to
//       the MFMA path) -> row list (~4 rows)
//   C)  exact fp64 cosine for listed rows; argmax, low-index tie-break
// margin 1.8e-2*qn = 14.9 sigma of i8 score error >= 2 x 6.2-sigma bound.
__global__ __launch_bounds__(256) void rescore_gather(
    const float* __restrict__ q, const float* __restrict__ mem,
    const int* __restrict__ qi8, const int* __restrict__ ki8,
    const float* __restrict__ rkn, const float* __restrict__ bmaxQ,
    const unsigned long long* __restrict__ bcode8, float* __restrict__ out) {
  __shared__ float red2[4];
  __shared__ int blist[64];
  __shared__ int nblk;
  __shared__ int glist[128];
  __shared__ int ng;
  __shared__ int rlist[256];
  __shared__ int nrow;
  __shared__ double wb[4];
  __shared__ int wbi[4];
  __shared__ int widx;

  const int qid = blockIdx.x;
  const int t = threadIdx.x, w = t >> 6, lane = t & 63;

  const float4 qv = *(const float4*)&q[(size_t)qid * 256 + lane * 4];
  float ss = qv.x * qv.x + qv.y * qv.y + qv.z * qv.z + qv.w * qv.w;
#pragma unroll
  for (int off = 32; off >= 1; off >>= 1) ss += __shfl_xor(ss, off, 64);
  const float qn = sqrtf(ss);
  const float margin = 1.8e-2f * qn;

  int4 qreg[4];
#pragma unroll
  for (int k = 0; k < 4; ++k)
    qreg[k] = *(const int4*)&qi8[(size_t)qid * 64 + (lane & 3) * 16 + k * 4];

  if (t == 0) { nblk = 0; ng = 0; nrow = 0; }
  const float* bq = &bmaxQ[(size_t)qid * BLKPAD];

  // ---- A ----
  float gm = -FLT_MAX;
  for (int i = t; i < NTILES; i += 256) gm = fmaxf(gm, bq[i]);
#pragma unroll
  for (int off = 32; off >= 1; off >>= 1) gm = fmaxf(gm, __shfl_xor(gm, off, 64));
  if (lane == 0) red2[w] = gm;
  __syncthreads();
  gm = fmaxf(fmaxf(red2[0], red2[1]), fmaxf(red2[2], red2[3]));
  const float thresh = gm - margin;

  for (int i = t; i < NTILES; i += 256)
    if (bq[i] >= thresh) {
      int p = atomicAdd(&nblk, 1);
      if (p < 64) blist[p] = i;
    }
  __syncthreads();
  const int nb_ = min(nblk, 64);

  // ---- B1: decode group codes (u64 broadcast across 8 threads) ----
  for (int idx = t; idx < nb_ * 8; idx += 256) {
    const int nt = blist[idx >> 3], gl = idx & 7;
    const unsigned long long cw = bcode8[(size_t)nt * NQ + qid];
    const int code = (int)((cw >> (8 * gl)) & 255);
    if ((float)code * GDELTA <= bq[nt] - thresh + 1e-6f) {
      int p = atomicAdd(&ng, 1);
      if (p < 128) glist[p] = nt * 8 + gl;   // rows = g*16 + 0..15
    }
  }
  __syncthreads();
  const int ng_ = min(ng, 128);

  // ---- B2: one candidate group per wave pass; 4 lanes per row ----
  for (int c = w; c < ng_; c += 4) {
    const int row = glist[c] * 16 + (lane >> 2);
    int idot = 0;
#pragma unroll
    for (int k = 0; k < 4; ++k) {
      const int4 kv = *(const int4*)&ki8[(size_t)row * 64 + (lane & 3) * 16 + k * 4];
      idot = dot4i8(kv.x, qreg[k].x, idot);
      idot = dot4i8(kv.y, qreg[k].y, idot);
      idot = dot4i8(kv.z, qreg[k].z, idot);
      idot = dot4i8(kv.w, qreg[k].w, idot);
    }
    idot += __shfl_xor(idot, 1, 64);
    idot += __shfl_xor(idot, 2, 64);
    if ((lane & 3) == 0 && row < NMEM) {
      const float sh = (float)idot * (rkn[row] * SS2);  // == gemm's value, bit-exact
      if (sh >= thresh) {
        int p = atomicAdd(&nrow, 1);
        if (p < 256) rlist[p] = row;
      }
    }
  }
  __syncthreads();
  const int nr = min(nrow, 256);

  // ---- C ----
  double bestv = -1e300;
  int bestidx = 0x7fffffff;
  for (int c = w; c < nr; c += 4) {
    const int row = rlist[c];
    const float4 kv = *(const float4*)&mem[(size_t)row * 512 + lane * 4];
    double d = (double)kv.x * qv.x + (double)kv.y * qv.y +
               (double)kv.z * qv.z + (double)kv.w * qv.w;
    double s2 = (double)kv.x * kv.x + (double)kv.y * kv.y +
                (double)kv.z * kv.z + (double)kv.w * kv.w;
#pragma unroll
    for (int off = 32; off >= 1; off >>= 1) {
      d += __shfl_xor(d, off, 64);
      s2 += __shfl_xor(s2, off, 64);
    }
    if (lane == 0) {
      const double score = d / sqrt(s2 > 1e-300 ? s2 : 1e-300);
      if (score > bestv || (score == bestv && row < bestidx)) {
        bestv = score;
        bestidx = row;
      }
    }
  }
  if (lane == 0) { wb[w] = bestv; wbi[w] = bestidx; }
  __syncthreads();
  if (t == 0) {
    double bv = wb[0];
    int bi = wbi[0];
#pragma unroll
    for (int w2 = 1; w2 < 4; ++w2)
      if (wb[w2] > bv || (wb[w2] == bv && wbi[w2] < bi)) {
        bv = wb[w2];
        bi = wbi[w2];
      }
    widx = bi;
  }
  __syncthreads();
  out[(size_t)qid * 256 + t] = mem[(size_t)widx * 512 + 256 + t];
}

extern "C" void kernel_launch(void* const* d_in, const int* in_sizes, int n_in,
                              void* d_out, int out_size, void* d_ws, size_t ws_size,
                              hipStream_t stream) {
  const float* query = (const float*)d_in[0];
  const float* memory = (const float*)d_in[1];
  float* out = (float*)d_out;

  char* p = (char*)d_ws;
  int* qi = (int*)p; p += (size_t)NQ * 64 * 4;               // 2 MB
  int* ki = (int*)p; p += (size_t)NPAD * 64 * 4;             // 25.6 MB
  float* rkn = (float*)p; p += (size_t)NPAD * 4;             // 0.4 MB
  float* bmaxB = (float*)p; p += (size_t)NTILES * NQ * 4;    // 6.4 MB
  float* bmaxQ = (float*)p; p += (size_t)NQ * BLKPAD * 4;    // 6.6 MB
  unsigned long long* bcode8 = (unsigned long long*)p;
  p += (size_t)NTILES * NQ * 8;                              // 12.8 MB

  hipLaunchKernelGGL(convert, dim3(KB16 + NQ * MKEY / 1024), dim3(256), 0, stream,
                     query, memory, qi, ki, rkn);
  hipLaunchKernelGGL(gemm_screen, dim3(GRID), dim3(256), 0, stream,
                     qi, ki, rkn, bcode8, bmaxB);
  hipLaunchKernelGGL(transpose_blk, dim3(25 * 64), dim3(256), 0, stream, bmaxB, bmaxQ);
  hipLaunchKernelGGL(rescore_gather, dim3(NQ), dim3(256), 0, stream,
                     query, memory, qi, ki, rkn, bmaxQ, bcode8, out);
}